// Round 10
// baseline (6212.047 us; speedup 1.0000x reference)
//
#include <hip/hip_runtime.h>
#include <float.h>

#define N_PTS 16384
#define M_PTS 4096
#define K_NN  16
#define CIN   64
#define COUT  64

typedef float v2f __attribute__((ext_vector_type(2)));
typedef unsigned long long ull;

// Exact f32 rounding to match numpy/jax: ((dx*dx + dy*dy) + dz*dz), no fma contraction.
__device__ __forceinline__ float dist2_exact(float ax, float ay, float az,
                                             float bx, float by, float bz) {
    float dx = __fsub_rn(ax, bx);
    float dy = __fsub_rn(ay, by);
    float dz = __fsub_rn(az, bz);
    return __fadd_rn(__fadd_rn(__fmul_rn(dx, dx), __fmul_rn(dy, dy)), __fmul_rn(dz, dz));
}

// Packed f32 ops via inline asm (v2f codegen otherwise scalarizes — R6 evidence).
__device__ __forceinline__ v2f pk_add(v2f a, v2f b) {
    v2f d; asm("v_pk_add_f32 %0, %1, %2" : "=v"(d) : "v"(a), "v"(b)); return d;
}
__device__ __forceinline__ v2f pk_mul(v2f a, v2f b) {
    v2f d; asm("v_pk_mul_f32 %0, %1, %2" : "=v"(d) : "v"(a), "v"(b)); return d;
}

// ---- DPP wave-64 reduction steps (idempotent ops -> full masks safe) ----
template <int CTRL>
__device__ __forceinline__ float dpp_fmax_step(float x) {
    int xi = __float_as_int(x);
    int yi = __builtin_amdgcn_update_dpp(xi, xi, CTRL, 0xf, 0xf, false);
    return fmaxf(x, __int_as_float(yi));
}
template <int CTRL>
__device__ __forceinline__ float dpp_fmin_step(float x) {
    int xi = __float_as_int(x);
    int yi = __builtin_amdgcn_update_dpp(xi, xi, CTRL, 0xf, 0xf, false);
    return fminf(x, __int_as_float(yi));
}
template <int CTRL>
__device__ __forceinline__ unsigned dpp_umin_step(unsigned x) {
    int xi = (int)x;
    unsigned y = (unsigned)__builtin_amdgcn_update_dpp(xi, xi, CTRL, 0xf, 0xf, false);
    return y < x ? y : x;
}
template <int CTRL>
__device__ __forceinline__ ull dpp_u64max_step(ull x) {
    int lo = (int)(unsigned)x;
    int hi = (int)(unsigned)(x >> 32);
    unsigned olo = (unsigned)__builtin_amdgcn_update_dpp(lo, lo, CTRL, 0xf, 0xf, false);
    unsigned ohi = (unsigned)__builtin_amdgcn_update_dpp(hi, hi, CTRL, 0xf, 0xf, false);
    ull o = ((ull)ohi << 32) | (ull)olo;
    return o > x ? o : x;
}
__device__ __forceinline__ unsigned wave_umin(unsigned x) {
    x = dpp_umin_step<0x111>(x);
    x = dpp_umin_step<0x112>(x);
    x = dpp_umin_step<0x114>(x);
    x = dpp_umin_step<0x118>(x);
    x = dpp_umin_step<0x142>(x);
    x = dpp_umin_step<0x143>(x);
    return (unsigned)__builtin_amdgcn_readlane((int)x, 63);
}
__device__ __forceinline__ float wave_fmax_f(float x) {
    x = dpp_fmax_step<0x111>(x);
    x = dpp_fmax_step<0x112>(x);
    x = dpp_fmax_step<0x114>(x);
    x = dpp_fmax_step<0x118>(x);
    x = dpp_fmax_step<0x142>(x);
    x = dpp_fmax_step<0x143>(x);
    return __int_as_float(__builtin_amdgcn_readlane(__float_as_int(x), 63));
}
__device__ __forceinline__ float wave_fmin_f(float x) {
    x = dpp_fmin_step<0x111>(x);
    x = dpp_fmin_step<0x112>(x);
    x = dpp_fmin_step<0x114>(x);
    x = dpp_fmin_step<0x118>(x);
    x = dpp_fmin_step<0x142>(x);
    x = dpp_fmin_step<0x143>(x);
    return __int_as_float(__builtin_amdgcn_readlane(__float_as_int(x), 63));
}

// Per-wave record extraction: wave max of d2 -> (val, qx, qy, qz, orig) in SGPRs.
// Scans use ONLY compile-time register indices; xy comes from LDS (runtime ok).
#define EXTRACT_RECORD()                                                          \
    {                                                                             \
        float _w = bv;                                                            \
        _w = dpp_fmax_step<0x111>(_w);                                            \
        _w = dpp_fmax_step<0x112>(_w);                                            \
        _w = dpp_fmax_step<0x114>(_w);                                            \
        _w = dpp_fmax_step<0x118>(_w);                                            \
        _w = dpp_fmax_step<0x142>(_w);                                            \
        _w = dpp_fmax_step<0x143>(_w);                                            \
        my_wval = __int_as_float(__builtin_amdgcn_readlane(__float_as_int(_w), 63)); \
        unsigned _kk = 0xffffffffu;                                               \
        float _cz = 0.0f;                                                         \
        _Pragma("unroll")                                                         \
        for (int _u = 0; _u < 16; ++_u) {                                         \
            const float _dv = (_u & 1) ? d2[_u >> 1].y : d2[_u >> 1].x;           \
            const unsigned _og = (_u & 1) ? (opk[_u >> 1] >> 16)                  \
                                          : (opk[_u >> 1] & 0xffffu);             \
            const unsigned _ky = (_og << 4) | (unsigned)_u;                       \
            const unsigned _uk = (_dv == my_wval) ? _ky : 0xffffffffu;            \
            if (_uk < _kk) {                                                      \
                _kk = _uk;                                                        \
                _cz = (_u & 1) ? zp[_u >> 1].y : zp[_u >> 1].x;                   \
            }                                                                     \
        }                                                                         \
        const unsigned _wkk = wave_umin(_kk);                                     \
        const ull _m = __ballot(_kk == _wkk);                                     \
        const int _wl = (int)__builtin_ctzll(_m);                                 \
        my_orig = _wkk >> 4;                                                      \
        const int _slot = (int)(_wkk & 15u);                                      \
        const int _wt = wv * 64 + _wl;                                            \
        const float4 _xy = s_xy4[_wt * 9 + (_slot >> 1)];                         \
        const float _qx = (_slot & 1) ? _xy.y : _xy.x;                            \
        const float _qy = (_slot & 1) ? _xy.w : _xy.z;                            \
        my_qx = __int_as_float(__builtin_amdgcn_readfirstlane(__float_as_int(_qx))); \
        my_qy = __int_as_float(__builtin_amdgcn_readfirstlane(__float_as_int(_qy))); \
        my_qz = __int_as_float(__builtin_amdgcn_readlane(__float_as_int(_cz), _wl)); \
    }

// ---------------------------------------------------------------------------
// Kernel 1: furthest point sampling, single-barrier persistent-record design
// (R9) + 2-D tile pruning (R10): points partitioned into a 4x4 grid of
// 1024-point tiles (two-pass bitonic: x-sort -> column id; re-key
// (col<<46 | y_bits<<14 | idx) -> second sort = y-sort within columns).
// A wave skips its update iff (gap_x^2 + gap_y^2) > wave max d2 — provably
// all-no-op (conservative bbox margins), so picks are bit-identical.
// ---------------------------------------------------------------------------
__global__ __launch_bounds__(1024) void fps_kernel(const float* __restrict__ p,
                                                   float* __restrict__ out) {
#pragma clang fp contract(off)
    const int t = threadIdx.x;
    const int lane = t & 63, wv = t >> 6;
    __shared__ char smem[147456];                      // keys[16384] then s_xy4[1024*9]
    __shared__ float s_pick[1024 * 3];                 // pick ring (12 KB)
    __shared__ float4 s_recf[2][16];                   // {val, qx, qy, qz}
    __shared__ unsigned s_reco[2][16];                 // orig

    ull* keys = (ull*)smem;
    float4* s_xy4 = (float4*)smem;

    // ---- Phase A pass 1: bitonic sort by x (keys unique via idx bits) ----
    for (int u = 0; u < 16; ++u) {
        const int j = u * 1024 + t;
        keys[j] = ((ull)__float_as_uint(p[3 * j]) << 32) | (unsigned)j;
    }
    __syncthreads();
    for (int k = 2; k <= N_PTS; k <<= 1) {
        for (int j = k >> 1; j > 0; j >>= 1) {
            for (int e = 0; e < 8; ++e) {
                const int c = e * 1024 + t;
                const int i1 = 2 * c - (c & (j - 1));
                const int i2 = i1 + j;
                const ull a = keys[i1], b = keys[i2];
                const bool up = ((i1 & k) == 0);
                if ((a > b) == up) { keys[i1] = b; keys[i2] = a; }
            }
            __syncthreads();
        }
    }

    // ---- pass 2 re-key in place: col = x-quartile of sorted slot (= t>>8
    // for all 16 slots of thread t), key2 = (col<<46)|(y_bits<<14)|idx.
    // Each slot is read+written only by its owner thread -> no hazard.
    {
        const ull colbits = ((ull)(t >> 8)) << 46;
        for (int u = 0; u < 16; ++u) {
            const int s = t * 16 + u;
            const unsigned j = (unsigned)keys[s];      // low32 = idx from pass 1
            const float y = p[3 * j + 1];
            keys[s] = colbits | ((ull)__float_as_uint(y) << 14) | (ull)j;
        }
    }
    __syncthreads();
    for (int k = 2; k <= N_PTS; k <<= 1) {
        for (int j = k >> 1; j > 0; j >>= 1) {
            for (int e = 0; e < 8; ++e) {
                const int c = e * 1024 + t;
                const int i1 = 2 * c - (c & (j - 1));
                const int i2 = i1 + j;
                const ull a = keys[i1], b = keys[i2];
                const bool up = ((i1 & k) == 0);
                if ((a > b) == up) { keys[i1] = b; keys[i2] = a; }
            }
            __syncthreads();
        }
    }

    // read own 16 sorted keys -> packed original indices (8 regs); idx = low 14 bits
    unsigned opk[8];
#pragma unroll
    for (int u = 0; u < 8; ++u) {
        const unsigned a = (unsigned)keys[t * 16 + 2 * u] & 0x3fffu;
        const unsigned b = (unsigned)keys[t * 16 + 2 * u + 1] & 0x3fffu;
        opk[u] = a | (b << 16);
    }
    __syncthreads();                                   // all key reads done before overwrite

    // ---- gather coords, build LDS xy ({x0,x1,y0,y1}) + reg z/d2, bbox, bv ----
    v2f zp[8], d2[8];
    const float q0x = p[0], q0y = p[1], q0z = p[2];
    float bv = -1.0f;
    float txmin = FLT_MAX, txmax = -FLT_MAX, tymin = FLT_MAX, tymax = -FLT_MAX;
#pragma unroll
    for (int u = 0; u < 8; ++u) {
        const int o0 = (int)(opk[u] & 0xffffu), o1 = (int)(opk[u] >> 16);
        const float x0 = p[3 * o0], y0 = p[3 * o0 + 1], z0 = p[3 * o0 + 2];
        const float x1 = p[3 * o1], y1 = p[3 * o1 + 1], z1 = p[3 * o1 + 2];
        s_xy4[t * 9 + u] = make_float4(x0, x1, y0, y1);
        zp[u] = (v2f){z0, z1};
        d2[u] = (v2f){dist2_exact(x0, y0, z0, q0x, q0y, q0z),
                      dist2_exact(x1, y1, z1, q0x, q0y, q0z)};
        bv = fmaxf(bv, fmaxf(d2[u].x, d2[u].y));
        txmin = fminf(txmin, fminf(x0, x1));
        txmax = fmaxf(txmax, fmaxf(x0, x1));
        tymin = fminf(tymin, fminf(y0, y1));
        tymax = fmaxf(tymax, fmaxf(y0, y1));
    }
    // tile (wave) bbox -> SGPR center/half-width with conservative slack
    const float wxmin = wave_fmin_f(txmin), wxmax = wave_fmax_f(txmax);
    const float wymin = wave_fmin_f(tymin), wymax = wave_fmax_f(tymax);
    const float cxw = 0.5f * (wxmin + wxmax);
    const float hwx = 0.5f * (wxmax - wxmin) + 1e-5f;
    const float cyw = 0.5f * (wymin + wymax);
    const float hwy = 0.5f * (wymax - wymin) + 1e-5f;

    // ---- initial per-wave record -> rec[1] (read at iter 1) ----
    float my_wval, my_qx, my_qy, my_qz;
    unsigned my_orig;
    EXTRACT_RECORD();
    if (lane == 0) {
        s_recf[1][wv] = make_float4(my_wval, my_qx, my_qy, my_qz);
        s_reco[1][wv] = my_orig;
    }
    if (t == 0) { s_pick[0] = q0x; s_pick[1] = q0y; s_pick[2] = q0z; }

    for (int i = 1; i < M_PTS; ++i) {
        const int par = i & 1;
        __syncthreads();                               // the ONE barrier per iteration

        // ring flush: once per 512 iters, previous 512-block (other ring half)
        if ((i & 511) == 0) {
            const int b = (i - 512) & 1023;
            const int base3 = (i - 512) * 3;
            out[base3 + t] = s_pick[b * 3 + t];
            if (t < 512) out[base3 + 1024 + t] = s_pick[b * 3 + 1024 + t];
        }

        // global winner from the 16 records: u64 key = (val_bits<<32 | ~orig)
        const int r = lane & 15;
        const float4 rf = s_recf[par][r];
        const unsigned ro = s_reco[par][r];
        ull key = ((ull)__float_as_uint(rf.x) << 32) | (ull)(~ro);
        ull red = key;
        red = dpp_u64max_step<0x111>(red);
        red = dpp_u64max_step<0x112>(red);
        red = dpp_u64max_step<0x114>(red);
        red = dpp_u64max_step<0x118>(red);
        const unsigned wlo = (unsigned)__builtin_amdgcn_readlane((int)(unsigned)red, 63);
        const unsigned whi = (unsigned)__builtin_amdgcn_readlane((int)(unsigned)(red >> 32), 63);
        const ull wk = ((ull)whi << 32) | (ull)wlo;
        const ull hm = __ballot(key == wk);
        const int hl = (int)__builtin_ctzll(hm);       // a lane holding the winner record
        const float qx = __int_as_float(__builtin_amdgcn_readlane(__float_as_int(rf.y), hl));
        const float qy = __int_as_float(__builtin_amdgcn_readlane(__float_as_int(rf.z), hl));
        const float qz = __int_as_float(__builtin_amdgcn_readlane(__float_as_int(rf.w), hl));
        if (t == 0) {
            const int s3 = (i & 1023) * 3;
            s_pick[s3] = qx; s_pick[s3 + 1] = qy; s_pick[s3 + 2] = qz;
        }

        // ---- 2-D tile prune: skip update iff provably all no-ops ----
        const float dxg = fmaxf(0.0f, fabsf(qx - cxw) - hwx);
        const float dyg = fmaxf(0.0f, fabsf(qy - cyw) - hwy);
        const bool active = (dxg * dxg + dyg * dyg <= my_wval);
        if (active) {
            const v2f nqx2 = (v2f){-qx, -qx};
            const v2f nqy2 = (v2f){-qy, -qy};
            const v2f nqz2 = (v2f){-qz, -qz};
            bv = -1.0f;
#pragma unroll
            for (int u = 0; u < 8; ++u) {
                const float4 xy = s_xy4[t * 9 + u];
                const v2f xp = (v2f){xy.x, xy.y};      // {x0,x1}
                const v2f yp = (v2f){xy.z, xy.w};      // {y0,y1}
                const v2f dx = pk_add(xp, nqx2);       // exact x - qx
                const v2f dy = pk_add(yp, nqy2);
                const v2f dz = pk_add(zp[u], nqz2);
                const v2f m1 = pk_mul(dx, dx);
                const v2f m2 = pk_mul(dy, dy);
                const v2f m3 = pk_mul(dz, dz);
                const v2f s = pk_add(pk_add(m1, m2), m3);  // ((x²+y²)+z²) exact order
                d2[u] = __builtin_elementwise_min(d2[u], s);
                bv = fmaxf(bv, fmaxf(d2[u].x, d2[u].y));
            }
            EXTRACT_RECORD();                          // refresh record (SGPRs)
        }
        // every wave posts its (possibly unchanged) record for the next iter
        if (lane == 0) {
            s_recf[1 - par][wv] = make_float4(my_wval, my_qx, my_qy, my_qz);
            s_reco[1 - par][wv] = my_orig;
        }
    }

    // final flush: picks 3584..4095 (ring half b=512) + n_o scalar
    __syncthreads();
    {
        const int base3 = 3584 * 3;
        const int b3 = 512 * 3;
        out[base3 + t] = s_pick[b3 + t];
        if (t < 512) out[base3 + 1024 + t] = s_pick[b3 + 1024 + t];
        if (t == 0) out[12288 + 786432] = 4096.0f;
    }
}

// ---------------------------------------------------------------------------
// Kernel 2: kNN (k=16) of each n_p among p. One wave per query, per-lane sorted
// top-16 in registers, lexicographic (d, idx) wave merge (matches top_k ties).
// ---------------------------------------------------------------------------
__global__ __launch_bounds__(256) void knn_kernel(const float* __restrict__ p,
                                                  const float* __restrict__ np_,
                                                  int* __restrict__ nn) {
    const int lane = threadIdx.x & 63;
    const int m = (blockIdx.x * 256 + threadIdx.x) >> 6;
    if (m >= M_PTS) return;

    const float qx = np_[3 * m], qy = np_[3 * m + 1], qz = np_[3 * m + 2];
    const float qq = __fadd_rn(__fadd_rn(__fmul_rn(qx, qx), __fmul_rn(qy, qy)),
                               __fmul_rn(qz, qz));
    float D[16]; int I[16];
#pragma unroll
    for (int s = 0; s < 16; ++s) { D[s] = FLT_MAX; I[s] = 0x7fffffff; }

    for (int c = 0; c < N_PTS / 64; ++c) {
        const int j = c * 64 + lane;
        const float px = p[3 * j], py = p[3 * j + 1], pz = p[3 * j + 2];
        const float pp = __fadd_rn(__fadd_rn(__fmul_rn(px, px), __fmul_rn(py, py)),
                                   __fmul_rn(pz, pz));
        const float qp = __fadd_rn(__fadd_rn(__fmul_rn(qx, px), __fmul_rn(qy, py)),
                                   __fmul_rn(qz, pz));
        const float d = __fadd_rn(__fsub_rn(qq, __fmul_rn(2.0f, qp)), pp);
        if (d < D[15]) {
            D[15] = d; I[15] = j;
#pragma unroll
            for (int s = 15; s > 0; --s) {
                if (D[s] < D[s - 1]) {
                    float tf = D[s]; D[s] = D[s - 1]; D[s - 1] = tf;
                    int   ti = I[s]; I[s] = I[s - 1]; I[s - 1] = ti;
                }
            }
        }
    }

    int myout = 0;
    for (int r = 0; r < 16; ++r) {
        float v = D[0]; int ix = I[0]; int bl = lane;
#pragma unroll
        for (int off = 1; off < 64; off <<= 1) {
            float ov = __shfl_xor(v, off);
            int   oi = __shfl_xor(ix, off);
            int   ol = __shfl_xor(bl, off);
            if (ov < v || (ov == v && oi < ix)) { v = ov; ix = oi; bl = ol; }
        }
        if (lane == bl) {
#pragma unroll
            for (int s = 0; s < 15; ++s) { D[s] = D[s + 1]; I[s] = I[s + 1]; }
            D[15] = FLT_MAX; I[15] = 0x7fffffff;
        }
        if (lane == r) myout = ix;
    }
    if (lane < K_NN) nn[m * K_NN + lane] = myout;
}

// ---------------------------------------------------------------------------
// Kernel 3: grouped VNLinearLeakyReLU + mean over nsample.
// One block per query m. W_feat/W_dir staged transposed in LDS; thread (o,i)
// accumulates over k. out layout (Cout,3,M): out[(o*3+i)*M + m].
// ---------------------------------------------------------------------------
__global__ __launch_bounds__(256) void vn_kernel(const float* __restrict__ x,
                                                 const float* __restrict__ Wf,
                                                 const float* __restrict__ Wd,
                                                 const int* __restrict__ nn,
                                                 float* __restrict__ out) {
    __shared__ float sWf[CIN * COUT];
    __shared__ float sWd[CIN * COUT];
    __shared__ float sg[CIN * 3];
    __shared__ float sq[COUT * 3];
    __shared__ float sd[COUT * 3];
    __shared__ float sf[COUT];

    const int m = blockIdx.x;
    const int tid = threadIdx.x;
    for (int u = tid; u < CIN * COUT; u += 256) {
        const int o = u >> 6, c = u & 63;
        sWf[c * 64 + o] = Wf[u];
        sWd[c * 64 + o] = Wd[u];
    }
    const int o = tid & 63, i = tid >> 6;
    const bool active = tid < 192;
    float acc = 0.0f;

    for (int k = 0; k < K_NN; ++k) {
        __syncthreads();
        const int j = nn[m * K_NN + k];
        if (tid < 192) sg[tid] = x[j * 192 + tid];
        __syncthreads();
        float qv = 0.0f, dv = 0.0f;
        if (active) {
#pragma unroll
            for (int c = 0; c < CIN; ++c) {
                const float g = sg[c * 3 + i];
                qv = fmaf(sWf[c * 64 + o], g, qv);
                dv = fmaf(sWd[c * 64 + o], g, dv);
            }
            sq[o * 3 + i] = qv;
            sd[o * 3 + i] = dv;
        }
        __syncthreads();
        if (tid < 64) {
            const float d0 = sd[tid * 3], d1 = sd[tid * 3 + 1], d2v = sd[tid * 3 + 2];
            const float q0 = sq[tid * 3], q1 = sq[tid * 3 + 1], q2 = sq[tid * 3 + 2];
            const float dot = q0 * d0 + q1 * d1 + q2 * d2v;
            const float dns = d0 * d0 + d1 * d1 + d2v * d2v + 1e-6f;
            sf[tid] = (dot >= 0.0f) ? 0.0f : 0.8f * (dot / dns);
        }
        __syncthreads();
        if (active) acc += qv - sf[o] * dv;
    }
    if (active) out[(o * 3 + i) * M_PTS + m] = acc * 0.0625f;
}

// ---------------------------------------------------------------------------
extern "C" void kernel_launch(void* const* d_in, const int* in_sizes, int n_in,
                              void* d_out, int out_size, void* d_ws, size_t ws_size,
                              hipStream_t stream) {
    const float* p  = (const float*)d_in[0];
    const float* x  = (const float*)d_in[1];
    const float* Wf = (const float*)d_in[2];
    const float* Wd = (const float*)d_in[3];
    float* out = (float*)d_out;
    int* nn = (int*)d_ws;

    fps_kernel<<<1, 1024, 0, stream>>>(p, out);
    knn_kernel<<<M_PTS / 4, 256, 0, stream>>>(p, out, nn);
    vn_kernel<<<M_PTS, 256, 0, stream>>>(x, Wf, Wd, nn, out + 12288);
}

// Round 11
// 6204.271 us; speedup vs baseline: 1.0013x; 1.0013x over previous
//
#include <hip/hip_runtime.h>
#include <float.h>

#define N_PTS 16384
#define M_PTS 4096
#define K_NN  16
#define CIN   64
#define COUT  64

typedef float v2f __attribute__((ext_vector_type(2)));
typedef unsigned long long ull;

// Exact f32 rounding to match numpy/jax: ((dx*dx + dy*dy) + dz*dz), no fma contraction.
__device__ __forceinline__ float dist2_exact(float ax, float ay, float az,
                                             float bx, float by, float bz) {
    float dx = __fsub_rn(ax, bx);
    float dy = __fsub_rn(ay, by);
    float dz = __fsub_rn(az, bz);
    return __fadd_rn(__fadd_rn(__fmul_rn(dx, dx), __fmul_rn(dy, dy)), __fmul_rn(dz, dz));
}

// Packed f32 ops via inline asm (v2f codegen otherwise scalarizes — R6 evidence).
__device__ __forceinline__ v2f pk_add(v2f a, v2f b) {
    v2f d; asm("v_pk_add_f32 %0, %1, %2" : "=v"(d) : "v"(a), "v"(b)); return d;
}
__device__ __forceinline__ v2f pk_mul(v2f a, v2f b) {
    v2f d; asm("v_pk_mul_f32 %0, %1, %2" : "=v"(d) : "v"(a), "v"(b)); return d;
}

// ---- DPP wave-64 reduction steps (idempotent ops -> full masks safe) ----
template <int CTRL>
__device__ __forceinline__ ull dpp_u64max_step(ull x) {
    int lo = (int)(unsigned)x;
    int hi = (int)(unsigned)(x >> 32);
    unsigned olo = (unsigned)__builtin_amdgcn_update_dpp(lo, lo, CTRL, 0xf, 0xf, false);
    unsigned ohi = (unsigned)__builtin_amdgcn_update_dpp(hi, hi, CTRL, 0xf, 0xf, false);
    ull o = ((ull)ohi << 32) | (ull)olo;
    return o > x ? o : x;
}
__device__ __forceinline__ float rdlane_f(float x, int l) {
    return __int_as_float(__builtin_amdgcn_readlane(__float_as_int(x), l));
}

// Wave-level reduce of the incremental (key, coords) winner: 6-step u64 DPP max
// -> lane63 broadcast -> ballot picks the holding lane -> coords via readlane.
// Replaces R9's scan+umin+LDS-read extract: the 16-slot equality scan, second
// DPP chain, and 120-cyc LDS coord read all leave the serial path.
#define REDUCE_RECORD()                                                           \
    {                                                                             \
        ull _r = kb;                                                              \
        _r = dpp_u64max_step<0x111>(_r);                                          \
        _r = dpp_u64max_step<0x112>(_r);                                          \
        _r = dpp_u64max_step<0x114>(_r);                                          \
        _r = dpp_u64max_step<0x118>(_r);                                          \
        _r = dpp_u64max_step<0x142>(_r);                                          \
        _r = dpp_u64max_step<0x143>(_r);                                          \
        const unsigned _lo = (unsigned)__builtin_amdgcn_readlane((int)(unsigned)_r, 63);  \
        const unsigned _hi = (unsigned)__builtin_amdgcn_readlane((int)(unsigned)(_r >> 32), 63); \
        my_k = ((ull)_hi << 32) | (ull)_lo;                                       \
        my_wval = __int_as_float((int)_hi);                                       \
        const ull _bm = __ballot(kb == my_k);                                     \
        const int _wl = (int)__builtin_ctzll(_bm);                                \
        my_qx = rdlane_f(cqx, _wl);                                               \
        my_qy = rdlane_f(cqy, _wl);                                               \
        my_qz = rdlane_f(cqz, _wl);                                               \
    }

// ---------------------------------------------------------------------------
// Kernel 1: furthest point sampling — R9 structure (single x-sort, x-slab wave
// prune, single barrier/iter, persistent records, LDS pick ring) with the
// extract chain shortened: winner key (d2_bits<<32 | ~orig) and coords are
// tracked incrementally during the min-update (cndmask), so the post-loop
// reduce is just one u64-DPP chain + ballot + readlanes. Tie-break ~orig =
// min original index among equal d2 = numpy argmax rule, bit-exact.
// ---------------------------------------------------------------------------
__global__ __launch_bounds__(1024) void fps_kernel(const float* __restrict__ p,
                                                   float* __restrict__ out) {
#pragma clang fp contract(off)
    const int t = threadIdx.x;
    const int lane = t & 63, wv = t >> 6;
    __shared__ char smem[147456];                      // keys[16384] then s_xy4[1024*9]
    __shared__ float s_pick[1024 * 3];                 // pick ring (12 KB)
    __shared__ ull s_reck[2][16];                      // record keys
    __shared__ float4 s_recc[2][16];                   // record coords {qx,qy,qz,-}

    ull* keys = (ull*)smem;
    float4* s_xy4 = (float4*)smem;

    // ---- Phase A: bitonic sort by x (keys unique via idx bits) ----
    for (int u = 0; u < 16; ++u) {
        const int j = u * 1024 + t;
        keys[j] = ((ull)__float_as_uint(p[3 * j]) << 32) | (unsigned)j;
    }
    __syncthreads();
    for (int k = 2; k <= N_PTS; k <<= 1) {
        for (int j = k >> 1; j > 0; j >>= 1) {
            for (int e = 0; e < 8; ++e) {
                const int c = e * 1024 + t;
                const int i1 = 2 * c - (c & (j - 1));
                const int i2 = i1 + j;
                const ull a = keys[i1], b = keys[i2];
                const bool up = ((i1 & k) == 0);
                if ((a > b) == up) { keys[i1] = b; keys[i2] = a; }
            }
            __syncthreads();
        }
    }

    // read own 16 sorted keys -> packed original indices (8 regs)
    unsigned opk[8];
#pragma unroll
    for (int u = 0; u < 8; ++u) {
        const ull a = keys[t * 16 + 2 * u];
        const ull b = keys[t * 16 + 2 * u + 1];
        opk[u] = ((unsigned)a & 0xffffu) | (((unsigned)b & 0xffffu) << 16);
    }
    __syncthreads();                                   // all key reads done before overwrite

    // ---- gather coords, build LDS xy ({x0,x1,y0,y1}) + reg z/d2, init winner ----
    v2f zp[8], d2[8];
    const float q0x = p[0], q0y = p[1], q0z = p[2];
    ull kb = 0;                                        // incremental winner key
    float cqx = 0.0f, cqy = 0.0f, cqz = 0.0f;          // incremental winner coords
    float xf = 0.0f, xl = 0.0f;
#pragma unroll
    for (int u = 0; u < 8; ++u) {
        const int o0 = (int)(opk[u] & 0xffffu), o1 = (int)(opk[u] >> 16);
        const float x0 = p[3 * o0], y0 = p[3 * o0 + 1], z0 = p[3 * o0 + 2];
        const float x1 = p[3 * o1], y1 = p[3 * o1 + 1], z1 = p[3 * o1 + 2];
        s_xy4[t * 9 + u] = make_float4(x0, x1, y0, y1);
        zp[u] = (v2f){z0, z1};
        d2[u] = (v2f){dist2_exact(x0, y0, z0, q0x, q0y, q0z),
                      dist2_exact(x1, y1, z1, q0x, q0y, q0z)};
        const ull k0 = ((ull)__float_as_uint(d2[u].x) << 32) | (ull)(~(opk[u] & 0xffffu));
        const ull k1 = ((ull)__float_as_uint(d2[u].y) << 32) | (ull)(~(opk[u] >> 16));
        if (k0 > kb) { kb = k0; cqx = x0; cqy = y0; cqz = z0; }
        if (k1 > kb) { kb = k1; cqx = x1; cqy = y1; cqz = z1; }
        if (u == 0) xf = x0;
        if (u == 7) xl = x1;
    }
    // wave x-slab bounds (sorted ascending: lane0/slot0 = min, lane63/slot15 = max)
    const float wxmin = rdlane_f(xf, 0);
    const float wxmax = rdlane_f(xl, 63);
    const float cx = 0.5f * (wxmin + wxmax);
    const float hw_safe = 0.5f * (wxmax - wxmin) + 1e-5f;   // slack >> fp32 rounding

    // ---- initial per-wave record -> rec[1] (read at iter 1) ----
    ull my_k; float my_wval, my_qx, my_qy, my_qz;
    REDUCE_RECORD();
    if (lane == 0) {
        s_reck[1][wv] = my_k;
        s_recc[1][wv] = make_float4(my_qx, my_qy, my_qz, 0.0f);
    }
    if (t == 0) { s_pick[0] = q0x; s_pick[1] = q0y; s_pick[2] = q0z; }

    for (int i = 1; i < M_PTS; ++i) {
        const int par = i & 1;
        __syncthreads();                               // the ONE barrier per iteration

        // ring flush: once per 512 iters, previous 512-block (other ring half)
        if ((i & 511) == 0) {
            const int b = (i - 512) & 1023;
            const int base3 = (i - 512) * 3;
            out[base3 + t] = s_pick[b * 3 + t];
            if (t < 512) out[base3 + 1024 + t] = s_pick[b * 3 + 1024 + t];
        }

        // global winner from the 16 preformed record keys
        const int r = lane & 15;
        const ull rkey = s_reck[par][r];
        const float4 rc = s_recc[par][r];
        ull red = rkey;
        red = dpp_u64max_step<0x111>(red);
        red = dpp_u64max_step<0x112>(red);
        red = dpp_u64max_step<0x114>(red);
        red = dpp_u64max_step<0x118>(red);
        const unsigned wlo = (unsigned)__builtin_amdgcn_readlane((int)(unsigned)red, 63);
        const unsigned whi = (unsigned)__builtin_amdgcn_readlane((int)(unsigned)(red >> 32), 63);
        const ull wk = ((ull)whi << 32) | (ull)wlo;
        const ull hm = __ballot(rkey == wk);
        const int hl = (int)__builtin_ctzll(hm);       // a lane holding the winner record
        const float qx = rdlane_f(rc.x, hl);
        const float qy = rdlane_f(rc.y, hl);
        const float qz = rdlane_f(rc.z, hl);
        if (t == 0) {
            const int s3 = (i & 1023) * 3;
            s_pick[s3] = qx; s_pick[s3 + 1] = qy; s_pick[s3 + 2] = qz;
        }

        // ---- wave-level slab prune: skip update iff provably all no-ops ----
        const float dxq = fabsf(qx - cx);
        bool active = true;
        if (dxq > hw_safe) {
            const float lb = dxq - hw_safe;            // conservative lower bound
            active = (lb * lb <= my_wval);
        }
        if (active) {
            const v2f nqx2 = (v2f){-qx, -qx};
            const v2f nqy2 = (v2f){-qy, -qy};
            const v2f nqz2 = (v2f){-qz, -qz};
            kb = 0; cqx = 0.0f; cqy = 0.0f; cqz = 0.0f;
#pragma unroll
            for (int u = 0; u < 8; ++u) {
                const float4 xy = s_xy4[t * 9 + u];
                const v2f xp = (v2f){xy.x, xy.y};      // {x0,x1}
                const v2f yp = (v2f){xy.z, xy.w};      // {y0,y1}
                const v2f dx = pk_add(xp, nqx2);       // exact x - qx
                const v2f dy = pk_add(yp, nqy2);
                const v2f dz = pk_add(zp[u], nqz2);
                const v2f m1 = pk_mul(dx, dx);
                const v2f m2 = pk_mul(dy, dy);
                const v2f m3 = pk_mul(dz, dz);
                const v2f s = pk_add(pk_add(m1, m2), m3);  // ((x²+y²)+z²) exact order
                d2[u] = __builtin_elementwise_min(d2[u], s);
                const ull k0 = ((ull)__float_as_uint(d2[u].x) << 32) | (ull)(~(opk[u] & 0xffffu));
                const ull k1 = ((ull)__float_as_uint(d2[u].y) << 32) | (ull)(~(opk[u] >> 16));
                if (k0 > kb) { kb = k0; cqx = xy.x; cqy = xy.z; cqz = zp[u].x; }
                if (k1 > kb) { kb = k1; cqx = xy.y; cqy = xy.w; cqz = zp[u].y; }
            }
            REDUCE_RECORD();                           // one u64-DPP chain + readlanes
        }
        // every wave posts its (possibly unchanged) record for the next iter
        if (lane == 0) {
            s_reck[1 - par][wv] = my_k;
            s_recc[1 - par][wv] = make_float4(my_qx, my_qy, my_qz, 0.0f);
        }
    }

    // final flush: picks 3584..4095 (ring half b=512) + n_o scalar
    __syncthreads();
    {
        const int base3 = 3584 * 3;
        const int b3 = 512 * 3;
        out[base3 + t] = s_pick[b3 + t];
        if (t < 512) out[base3 + 1024 + t] = s_pick[b3 + 1024 + t];
        if (t == 0) out[12288 + 786432] = 4096.0f;
    }
}

// ---------------------------------------------------------------------------
// Kernel 2: kNN (k=16) of each n_p among p. One wave per query, per-lane sorted
// top-16 in registers, lexicographic (d, idx) wave merge (matches top_k ties).
// ---------------------------------------------------------------------------
__global__ __launch_bounds__(256) void knn_kernel(const float* __restrict__ p,
                                                  const float* __restrict__ np_,
                                                  int* __restrict__ nn) {
    const int lane = threadIdx.x & 63;
    const int m = (blockIdx.x * 256 + threadIdx.x) >> 6;
    if (m >= M_PTS) return;

    const float qx = np_[3 * m], qy = np_[3 * m + 1], qz = np_[3 * m + 2];
    const float qq = __fadd_rn(__fadd_rn(__fmul_rn(qx, qx), __fmul_rn(qy, qy)),
                               __fmul_rn(qz, qz));
    float D[16]; int I[16];
#pragma unroll
    for (int s = 0; s < 16; ++s) { D[s] = FLT_MAX; I[s] = 0x7fffffff; }

    for (int c = 0; c < N_PTS / 64; ++c) {
        const int j = c * 64 + lane;
        const float px = p[3 * j], py = p[3 * j + 1], pz = p[3 * j + 2];
        const float pp = __fadd_rn(__fadd_rn(__fmul_rn(px, px), __fmul_rn(py, py)),
                                   __fmul_rn(pz, pz));
        const float qp = __fadd_rn(__fadd_rn(__fmul_rn(qx, px), __fmul_rn(qy, py)),
                                   __fmul_rn(qz, pz));
        const float d = __fadd_rn(__fsub_rn(qq, __fmul_rn(2.0f, qp)), pp);
        if (d < D[15]) {
            D[15] = d; I[15] = j;
#pragma unroll
            for (int s = 15; s > 0; --s) {
                if (D[s] < D[s - 1]) {
                    float tf = D[s]; D[s] = D[s - 1]; D[s - 1] = tf;
                    int   ti = I[s]; I[s] = I[s - 1]; I[s - 1] = ti;
                }
            }
        }
    }

    int myout = 0;
    for (int r = 0; r < 16; ++r) {
        float v = D[0]; int ix = I[0]; int bl = lane;
#pragma unroll
        for (int off = 1; off < 64; off <<= 1) {
            float ov = __shfl_xor(v, off);
            int   oi = __shfl_xor(ix, off);
            int   ol = __shfl_xor(bl, off);
            if (ov < v || (ov == v && oi < ix)) { v = ov; ix = oi; bl = ol; }
        }
        if (lane == bl) {
#pragma unroll
            for (int s = 0; s < 15; ++s) { D[s] = D[s + 1]; I[s] = I[s + 1]; }
            D[15] = FLT_MAX; I[15] = 0x7fffffff;
        }
        if (lane == r) myout = ix;
    }
    if (lane < K_NN) nn[m * K_NN + lane] = myout;
}

// ---------------------------------------------------------------------------
// Kernel 3: grouped VNLinearLeakyReLU + mean over nsample.
// One block per query m. W_feat/W_dir staged transposed in LDS; thread (o,i)
// accumulates over k. out layout (Cout,3,M): out[(o*3+i)*M + m].
// ---------------------------------------------------------------------------
__global__ __launch_bounds__(256) void vn_kernel(const float* __restrict__ x,
                                                 const float* __restrict__ Wf,
                                                 const float* __restrict__ Wd,
                                                 const int* __restrict__ nn,
                                                 float* __restrict__ out) {
    __shared__ float sWf[CIN * COUT];
    __shared__ float sWd[CIN * COUT];
    __shared__ float sg[CIN * 3];
    __shared__ float sq[COUT * 3];
    __shared__ float sd[COUT * 3];
    __shared__ float sf[COUT];

    const int m = blockIdx.x;
    const int tid = threadIdx.x;
    for (int u = tid; u < CIN * COUT; u += 256) {
        const int o = u >> 6, c = u & 63;
        sWf[c * 64 + o] = Wf[u];
        sWd[c * 64 + o] = Wd[u];
    }
    const int o = tid & 63, i = tid >> 6;
    const bool active = tid < 192;
    float acc = 0.0f;

    for (int k = 0; k < K_NN; ++k) {
        __syncthreads();
        const int j = nn[m * K_NN + k];
        if (tid < 192) sg[tid] = x[j * 192 + tid];
        __syncthreads();
        float qv = 0.0f, dv = 0.0f;
        if (active) {
#pragma unroll
            for (int c = 0; c < CIN; ++c) {
                const float g = sg[c * 3 + i];
                qv = fmaf(sWf[c * 64 + o], g, qv);
                dv = fmaf(sWd[c * 64 + o], g, dv);
            }
            sq[o * 3 + i] = qv;
            sd[o * 3 + i] = dv;
        }
        __syncthreads();
        if (tid < 64) {
            const float d0 = sd[tid * 3], d1 = sd[tid * 3 + 1], d2v = sd[tid * 3 + 2];
            const float q0 = sq[tid * 3], q1 = sq[tid * 3 + 1], q2 = sq[tid * 3 + 2];
            const float dot = q0 * d0 + q1 * d1 + q2 * d2v;
            const float dns = d0 * d0 + d1 * d1 + d2v * d2v + 1e-6f;
            sf[tid] = (dot >= 0.0f) ? 0.0f : 0.8f * (dot / dns);
        }
        __syncthreads();
        if (active) acc += qv - sf[o] * dv;
    }
    if (active) out[(o * 3 + i) * M_PTS + m] = acc * 0.0625f;
}

// ---------------------------------------------------------------------------
extern "C" void kernel_launch(void* const* d_in, const int* in_sizes, int n_in,
                              void* d_out, int out_size, void* d_ws, size_t ws_size,
                              hipStream_t stream) {
    const float* p  = (const float*)d_in[0];
    const float* x  = (const float*)d_in[1];
    const float* Wf = (const float*)d_in[2];
    const float* Wd = (const float*)d_in[3];
    float* out = (float*)d_out;
    int* nn = (int*)d_ws;

    fps_kernel<<<1, 1024, 0, stream>>>(p, out);
    knn_kernel<<<M_PTS / 4, 256, 0, stream>>>(p, out, nn);
    vn_kernel<<<M_PTS, 256, 0, stream>>>(x, Wf, Wd, nn, out + 12288);
}

// Round 12
// 5598.789 us; speedup vs baseline: 1.1095x; 1.1081x over previous
//
#include <hip/hip_runtime.h>
#include <float.h>

#define N_PTS 16384
#define M_PTS 4096
#define K_NN  16
#define CIN   64
#define COUT  64

typedef float v2f __attribute__((ext_vector_type(2)));
typedef unsigned long long ull;

// Exact f32 rounding to match numpy/jax: ((dx*dx + dy*dy) + dz*dz), no fma contraction.
__device__ __forceinline__ float dist2_exact(float ax, float ay, float az,
                                             float bx, float by, float bz) {
    float dx = __fsub_rn(ax, bx);
    float dy = __fsub_rn(ay, by);
    float dz = __fsub_rn(az, bz);
    return __fadd_rn(__fadd_rn(__fmul_rn(dx, dx), __fmul_rn(dy, dy)), __fmul_rn(dz, dz));
}

// Packed f32 ops via inline asm (v2f codegen otherwise scalarizes — R6 evidence).
__device__ __forceinline__ v2f pk_add(v2f a, v2f b) {
    v2f d; asm("v_pk_add_f32 %0, %1, %2" : "=v"(d) : "v"(a), "v"(b)); return d;
}
__device__ __forceinline__ v2f pk_mul(v2f a, v2f b) {
    v2f d; asm("v_pk_mul_f32 %0, %1, %2" : "=v"(d) : "v"(a), "v"(b)); return d;
}

// ---- DPP wave-64 reduction steps (idempotent ops -> full masks safe) ----
template <int CTRL>
__device__ __forceinline__ float dpp_fmax_step(float x) {
    int xi = __float_as_int(x);
    int yi = __builtin_amdgcn_update_dpp(xi, xi, CTRL, 0xf, 0xf, false);
    return fmaxf(x, __int_as_float(yi));
}
template <int CTRL>
__device__ __forceinline__ unsigned dpp_umin_step(unsigned x) {
    int xi = (int)x;
    unsigned y = (unsigned)__builtin_amdgcn_update_dpp(xi, xi, CTRL, 0xf, 0xf, false);
    return y < x ? y : x;
}
template <int CTRL>
__device__ __forceinline__ ull dpp_u64max_step(ull x) {
    int lo = (int)(unsigned)x;
    int hi = (int)(unsigned)(x >> 32);
    unsigned olo = (unsigned)__builtin_amdgcn_update_dpp(lo, lo, CTRL, 0xf, 0xf, false);
    unsigned ohi = (unsigned)__builtin_amdgcn_update_dpp(hi, hi, CTRL, 0xf, 0xf, false);
    ull o = ((ull)ohi << 32) | (ull)olo;
    return o > x ? o : x;
}
__device__ __forceinline__ unsigned wave_umin(unsigned x) {
    x = dpp_umin_step<0x111>(x);
    x = dpp_umin_step<0x112>(x);
    x = dpp_umin_step<0x114>(x);
    x = dpp_umin_step<0x118>(x);
    x = dpp_umin_step<0x142>(x);
    x = dpp_umin_step<0x143>(x);
    return (unsigned)__builtin_amdgcn_readlane((int)x, 63);
}

// Per-wave record extraction: wave max of d2 -> (val, qx, qy, qz, orig) in SGPRs.
// Scans use ONLY compile-time register indices; xy comes from LDS (runtime ok).
#define EXTRACT_RECORD()                                                          \
    {                                                                             \
        float _w = bv;                                                            \
        _w = dpp_fmax_step<0x111>(_w);                                            \
        _w = dpp_fmax_step<0x112>(_w);                                            \
        _w = dpp_fmax_step<0x114>(_w);                                            \
        _w = dpp_fmax_step<0x118>(_w);                                            \
        _w = dpp_fmax_step<0x142>(_w);                                            \
        _w = dpp_fmax_step<0x143>(_w);                                            \
        my_wval = __int_as_float(__builtin_amdgcn_readlane(__float_as_int(_w), 63)); \
        unsigned _kk = 0xffffffffu;                                               \
        float _cz = 0.0f;                                                         \
        _Pragma("unroll")                                                         \
        for (int _u = 0; _u < 16; ++_u) {                                         \
            const float _dv = (_u & 1) ? d2[_u >> 1].y : d2[_u >> 1].x;           \
            const unsigned _og = (_u & 1) ? (opk[_u >> 1] >> 16)                  \
                                          : (opk[_u >> 1] & 0xffffu);             \
            const unsigned _ky = (_og << 4) | (unsigned)_u;                       \
            const unsigned _uk = (_dv == my_wval) ? _ky : 0xffffffffu;            \
            if (_uk < _kk) {                                                      \
                _kk = _uk;                                                        \
                _cz = (_u & 1) ? zp[_u >> 1].y : zp[_u >> 1].x;                   \
            }                                                                     \
        }                                                                         \
        const unsigned _wkk = wave_umin(_kk);                                     \
        const ull _m = __ballot(_kk == _wkk);                                     \
        const int _wl = (int)__builtin_ctzll(_m);                                 \
        my_orig = _wkk >> 4;                                                      \
        const int _slot = (int)(_wkk & 15u);                                      \
        const int _wt = wv * 64 + _wl;                                            \
        const float4 _xy = s_xy4[_wt * 9 + (_slot >> 1)];                         \
        const float _qx = (_slot & 1) ? _xy.y : _xy.x;                            \
        const float _qy = (_slot & 1) ? _xy.w : _xy.z;                            \
        my_qx = __int_as_float(__builtin_amdgcn_readfirstlane(__float_as_int(_qx))); \
        my_qy = __int_as_float(__builtin_amdgcn_readfirstlane(__float_as_int(_qy))); \
        my_qz = __int_as_float(__builtin_amdgcn_readlane(__float_as_int(_cz), _wl)); \
    }

// ---------------------------------------------------------------------------
// Kernel 1: furthest point sampling — EXACT R9 kernel (best measured: 5182 µs).
// Single-barrier persistent-record design + x-slab wave prune. R10 (2-D tile)
// and R11 (incremental key) both regressed it — this is the measured floor.
// ---------------------------------------------------------------------------
__global__ __launch_bounds__(1024) void fps_kernel(const float* __restrict__ p,
                                                   float* __restrict__ out) {
#pragma clang fp contract(off)
    const int t = threadIdx.x;
    const int lane = t & 63, wv = t >> 6;
    __shared__ char smem[147456];                      // keys[16384] then s_xy4[1024*9]
    __shared__ float s_pick[1024 * 3];                 // pick ring (12 KB)
    __shared__ float4 s_recf[2][16];                   // {val, qx, qy, qz}
    __shared__ unsigned s_reco[2][16];                 // orig

    ull* keys = (ull*)smem;
    float4* s_xy4 = (float4*)smem;

    // ---- Phase A: bitonic sort by x (keys unique via idx bits) ----
    for (int u = 0; u < 16; ++u) {
        const int j = u * 1024 + t;
        keys[j] = ((ull)__float_as_uint(p[3 * j]) << 32) | (unsigned)j;
    }
    __syncthreads();
    for (int k = 2; k <= N_PTS; k <<= 1) {
        for (int j = k >> 1; j > 0; j >>= 1) {
            for (int e = 0; e < 8; ++e) {
                const int c = e * 1024 + t;
                const int i1 = 2 * c - (c & (j - 1));
                const int i2 = i1 + j;
                const ull a = keys[i1], b = keys[i2];
                const bool up = ((i1 & k) == 0);
                if ((a > b) == up) { keys[i1] = b; keys[i2] = a; }
            }
            __syncthreads();
        }
    }

    // read own 16 sorted keys -> packed original indices (8 regs)
    unsigned opk[8];
#pragma unroll
    for (int u = 0; u < 8; ++u) {
        const ull a = keys[t * 16 + 2 * u];
        const ull b = keys[t * 16 + 2 * u + 1];
        opk[u] = ((unsigned)a & 0xffffu) | (((unsigned)b & 0xffffu) << 16);
    }
    __syncthreads();                                   // all key reads done before overwrite

    // ---- gather coords, build LDS xy ({x0,x1,y0,y1}) + reg z/d2, init bv ----
    v2f zp[8], d2[8];
    const float q0x = p[0], q0y = p[1], q0z = p[2];
    float bv = -1.0f;
    float xf = 0.0f, xl = 0.0f;
#pragma unroll
    for (int u = 0; u < 8; ++u) {
        const int o0 = (int)(opk[u] & 0xffffu), o1 = (int)(opk[u] >> 16);
        const float x0 = p[3 * o0], y0 = p[3 * o0 + 1], z0 = p[3 * o0 + 2];
        const float x1 = p[3 * o1], y1 = p[3 * o1 + 1], z1 = p[3 * o1 + 2];
        s_xy4[t * 9 + u] = make_float4(x0, x1, y0, y1);
        zp[u] = (v2f){z0, z1};
        d2[u] = (v2f){dist2_exact(x0, y0, z0, q0x, q0y, q0z),
                      dist2_exact(x1, y1, z1, q0x, q0y, q0z)};
        bv = fmaxf(bv, fmaxf(d2[u].x, d2[u].y));
        if (u == 0) xf = x0;
        if (u == 7) xl = x1;
    }
    // wave x-slab bounds (sorted ascending: lane0/slot0 = min, lane63/slot15 = max)
    const float wxmin = __int_as_float(__builtin_amdgcn_readlane(__float_as_int(xf), 0));
    const float wxmax = __int_as_float(__builtin_amdgcn_readlane(__float_as_int(xl), 63));
    const float cx = 0.5f * (wxmin + wxmax);
    const float hw_safe = 0.5f * (wxmax - wxmin) + 1e-5f;   // slack >> fp32 rounding

    // ---- initial per-wave record -> rec[1] (read at iter 1) ----
    float my_wval, my_qx, my_qy, my_qz;
    unsigned my_orig;
    EXTRACT_RECORD();
    if (lane == 0) {
        s_recf[1][wv] = make_float4(my_wval, my_qx, my_qy, my_qz);
        s_reco[1][wv] = my_orig;
    }
    if (t == 0) { s_pick[0] = q0x; s_pick[1] = q0y; s_pick[2] = q0z; }

    for (int i = 1; i < M_PTS; ++i) {
        const int par = i & 1;
        __syncthreads();                               // the ONE barrier per iteration

        // ring flush: once per 512 iters, previous 512-block (other ring half)
        if ((i & 511) == 0) {
            const int b = (i - 512) & 1023;
            const int base3 = (i - 512) * 3;
            out[base3 + t] = s_pick[b * 3 + t];
            if (t < 512) out[base3 + 1024 + t] = s_pick[b * 3 + 1024 + t];
        }

        // global winner from the 16 records: u64 key = (val_bits<<32 | ~orig)
        const int r = lane & 15;
        const float4 rf = s_recf[par][r];
        const unsigned ro = s_reco[par][r];
        ull key = ((ull)__float_as_uint(rf.x) << 32) | (ull)(~ro);
        ull red = key;
        red = dpp_u64max_step<0x111>(red);
        red = dpp_u64max_step<0x112>(red);
        red = dpp_u64max_step<0x114>(red);
        red = dpp_u64max_step<0x118>(red);
        const unsigned wlo = (unsigned)__builtin_amdgcn_readlane((int)(unsigned)red, 63);
        const unsigned whi = (unsigned)__builtin_amdgcn_readlane((int)(unsigned)(red >> 32), 63);
        const ull wk = ((ull)whi << 32) | (ull)wlo;
        const ull hm = __ballot(key == wk);
        const int hl = (int)__builtin_ctzll(hm);       // a lane holding the winner record
        const float qx = __int_as_float(__builtin_amdgcn_readlane(__float_as_int(rf.y), hl));
        const float qy = __int_as_float(__builtin_amdgcn_readlane(__float_as_int(rf.z), hl));
        const float qz = __int_as_float(__builtin_amdgcn_readlane(__float_as_int(rf.w), hl));
        if (t == 0) {
            const int s3 = (i & 1023) * 3;
            s_pick[s3] = qx; s_pick[s3 + 1] = qy; s_pick[s3 + 2] = qz;
        }

        // ---- wave-level slab prune: skip update iff provably all no-ops ----
        const float dxq = fabsf(qx - cx);
        bool active = true;
        if (dxq > hw_safe) {
            const float lb = dxq - hw_safe;            // conservative lower bound
            active = (lb * lb <= my_wval);
        }
        if (active) {
            const v2f nqx2 = (v2f){-qx, -qx};
            const v2f nqy2 = (v2f){-qy, -qy};
            const v2f nqz2 = (v2f){-qz, -qz};
            bv = -1.0f;
#pragma unroll
            for (int u = 0; u < 8; ++u) {
                const float4 xy = s_xy4[t * 9 + u];
                const v2f xp = (v2f){xy.x, xy.y};      // {x0,x1}
                const v2f yp = (v2f){xy.z, xy.w};      // {y0,y1}
                const v2f dx = pk_add(xp, nqx2);       // exact x - qx
                const v2f dy = pk_add(yp, nqy2);
                const v2f dz = pk_add(zp[u], nqz2);
                const v2f m1 = pk_mul(dx, dx);
                const v2f m2 = pk_mul(dy, dy);
                const v2f m3 = pk_mul(dz, dz);
                const v2f s = pk_add(pk_add(m1, m2), m3);  // ((x²+y²)+z²) exact order
                d2[u] = __builtin_elementwise_min(d2[u], s);
                bv = fmaxf(bv, fmaxf(d2[u].x, d2[u].y));
            }
            EXTRACT_RECORD();                          // refresh record (SGPRs)
        }
        // every wave posts its (possibly unchanged) record for the next iter
        if (lane == 0) {
            s_recf[1 - par][wv] = make_float4(my_wval, my_qx, my_qy, my_qz);
            s_reco[1 - par][wv] = my_orig;
        }
    }

    // final flush: picks 3584..4095 (ring half b=512) + n_o scalar
    __syncthreads();
    {
        const int base3 = 3584 * 3;
        const int b3 = 512 * 3;
        out[base3 + t] = s_pick[b3 + t];
        if (t < 512) out[base3 + 1024 + t] = s_pick[b3 + 1024 + t];
        if (t == 0) out[12288 + 786432] = 4096.0f;
    }
}

// ---------------------------------------------------------------------------
// Kernel 2: kNN (k=16) of each n_p among p. One wave per query, per-lane sorted
// top-16 in registers, lexicographic (d, idx) wave merge (matches top_k ties).
// Unchanged from R9 (isolating the vn rewrite).
// ---------------------------------------------------------------------------
__global__ __launch_bounds__(256) void knn_kernel(const float* __restrict__ p,
                                                  const float* __restrict__ np_,
                                                  int* __restrict__ nn) {
    const int lane = threadIdx.x & 63;
    const int m = (blockIdx.x * 256 + threadIdx.x) >> 6;
    if (m >= M_PTS) return;

    const float qx = np_[3 * m], qy = np_[3 * m + 1], qz = np_[3 * m + 2];
    const float qq = __fadd_rn(__fadd_rn(__fmul_rn(qx, qx), __fmul_rn(qy, qy)),
                               __fmul_rn(qz, qz));
    float D[16]; int I[16];
#pragma unroll
    for (int s = 0; s < 16; ++s) { D[s] = FLT_MAX; I[s] = 0x7fffffff; }

    for (int c = 0; c < N_PTS / 64; ++c) {
        const int j = c * 64 + lane;
        const float px = p[3 * j], py = p[3 * j + 1], pz = p[3 * j + 2];
        const float pp = __fadd_rn(__fadd_rn(__fmul_rn(px, px), __fmul_rn(py, py)),
                                   __fmul_rn(pz, pz));
        const float qp = __fadd_rn(__fadd_rn(__fmul_rn(qx, px), __fmul_rn(qy, py)),
                                   __fmul_rn(qz, pz));
        const float d = __fadd_rn(__fsub_rn(qq, __fmul_rn(2.0f, qp)), pp);
        if (d < D[15]) {
            D[15] = d; I[15] = j;
#pragma unroll
            for (int s = 15; s > 0; --s) {
                if (D[s] < D[s - 1]) {
                    float tf = D[s]; D[s] = D[s - 1]; D[s - 1] = tf;
                    int   ti = I[s]; I[s] = I[s - 1]; I[s - 1] = ti;
                }
            }
        }
    }

    int myout = 0;
    for (int r = 0; r < 16; ++r) {
        float v = D[0]; int ix = I[0]; int bl = lane;
#pragma unroll
        for (int off = 1; off < 64; off <<= 1) {
            float ov = __shfl_xor(v, off);
            int   oi = __shfl_xor(ix, off);
            int   ol = __shfl_xor(bl, off);
            if (ov < v || (ov == v && oi < ix)) { v = ov; ix = oi; bl = ol; }
        }
        if (lane == bl) {
#pragma unroll
            for (int s = 0; s < 15; ++s) { D[s] = D[s + 1]; I[s] = I[s + 1]; }
            D[15] = FLT_MAX; I[15] = 0x7fffffff;
        }
        if (lane == r) myout = ix;
    }
    if (lane < K_NN) nn[m * K_NN + lane] = myout;
}

// ---------------------------------------------------------------------------
// Kernel 3 (R12 rewrite): VNLinearLeakyReLU + mean, thread-per-(query,o).
// Block = 4 queries x 64 o-threads. All 16 neighbors' g for all 4 queries
// preloaded to LDS (2 barriers total vs 64). W reads conflict-free across o;
// g reads wave-uniform broadcasts (free). dot/dns/leaky-act thread-local.
// ---------------------------------------------------------------------------
__global__ __launch_bounds__(256) void vn_kernel(const float* __restrict__ x,
                                                 const float* __restrict__ Wf,
                                                 const float* __restrict__ Wd,
                                                 const int* __restrict__ nn,
                                                 float* __restrict__ out) {
    __shared__ float sWf[CIN * COUT];                  // [c*64+o] transposed
    __shared__ float sWd[CIN * COUT];
    __shared__ float sg[4 * K_NN * 192];               // [qi][k][c*3+i]  (48 KB)
    __shared__ int snn[64];

    const int tid = threadIdx.x;
    const int m0 = blockIdx.x * 4;
    for (int u = tid; u < CIN * COUT; u += 256) {
        const int o = u >> 6, c = u & 63;
        sWf[c * 64 + o] = Wf[u];
        sWd[c * 64 + o] = Wd[u];
    }
    if (tid < 64) snn[tid] = nn[m0 * K_NN + tid];
    __syncthreads();

    // gather all neighbor features: 12288 floats, coalesced in 192-runs
    for (int idx = tid; idx < 4 * K_NN * 192; idx += 256) {
        const int pair = idx / 192;                    // qi*16 + k
        const int c3 = idx - pair * 192;
        sg[idx] = x[snn[pair] * 192 + c3];
    }
    __syncthreads();

    const int qi = tid >> 6, o = tid & 63;
    const float* g = &sg[qi * K_NN * 192];
    float a0 = 0.0f, a1 = 0.0f, a2 = 0.0f;
    for (int k = 0; k < K_NN; ++k) {
        const float* gk = &g[k * 192];
        float q0 = 0.0f, q1 = 0.0f, q2 = 0.0f;
        float d0 = 0.0f, d1 = 0.0f, d2v = 0.0f;
#pragma unroll 8
        for (int c = 0; c < CIN; ++c) {
            const float wf = sWf[c * 64 + o];
            const float wd = sWd[c * 64 + o];
            const float g0 = gk[c * 3], g1 = gk[c * 3 + 1], g2 = gk[c * 3 + 2];
            q0 = fmaf(wf, g0, q0); q1 = fmaf(wf, g1, q1); q2 = fmaf(wf, g2, q2);
            d0 = fmaf(wd, g0, d0); d1 = fmaf(wd, g1, d1); d2v = fmaf(wd, g2, d2v);
        }
        const float dot = q0 * d0 + q1 * d1 + q2 * d2v;
        const float dns = d0 * d0 + d1 * d1 + d2v * d2v + 1e-6f;
        const float f = (dot >= 0.0f) ? 0.0f : 0.8f * (dot / dns);
        a0 += q0 - f * d0;
        a1 += q1 - f * d1;
        a2 += q2 - f * d2v;
    }
    const int m = m0 + qi;
    out[(o * 3 + 0) * M_PTS + m] = a0 * 0.0625f;       // mean over 16
    out[(o * 3 + 1) * M_PTS + m] = a1 * 0.0625f;
    out[(o * 3 + 2) * M_PTS + m] = a2 * 0.0625f;
}

// ---------------------------------------------------------------------------
extern "C" void kernel_launch(void* const* d_in, const int* in_sizes, int n_in,
                              void* d_out, int out_size, void* d_ws, size_t ws_size,
                              hipStream_t stream) {
    const float* p  = (const float*)d_in[0];
    const float* x  = (const float*)d_in[1];
    const float* Wf = (const float*)d_in[2];
    const float* Wd = (const float*)d_in[3];
    float* out = (float*)d_out;
    int* nn = (int*)d_ws;

    fps_kernel<<<1, 1024, 0, stream>>>(p, out);
    knn_kernel<<<M_PTS / 4, 256, 0, stream>>>(p, out, nn);
    vn_kernel<<<M_PTS / 4, 256, 0, stream>>>(x, Wf, Wd, nn, out + 12288);
}